// Round 7
// baseline (91.660 us; speedup 1.0000x reference)
//
#include <hip/hip_runtime.h>
#include <hip/hip_bf16.h>

typedef float          f32x4  __attribute__((ext_vector_type(4)));
typedef __bf16         bf16x8 __attribute__((ext_vector_type(8)));
typedef unsigned short u16x8  __attribute__((ext_vector_type(8)));
typedef unsigned int   u32;

#define DEV static __device__ __forceinline__

static constexpr int   NT      = 65536;                 // (262144*4)/16 16-row tiles
static constexpr float SCALE_Q = 0.17677669529663687f;  // 1/sqrt(32)
static constexpr float LOG2E   = 1.44269504f;

DEV unsigned short f2bf(float f) {
  return __builtin_bit_cast(unsigned short, __float2bfloat16(f));
}
DEV u32 pk2(float lo, float hi) { return (u32)f2bf(lo) | ((u32)f2bf(hi) << 16); }

DEV u16x8 pack8(f32x4 a, f32x4 b) {
  uint4 q;
  q.x = pk2(a[0], a[1]); q.y = pk2(a[2], a[3]);
  q.z = pk2(b[0], b[1]); q.w = pk2(b[2], b[3]);
  return __builtin_bit_cast(u16x8, q);
}

DEV f32x4 mfma(u16x8 a, u16x8 b, f32x4 c) {
  return __builtin_amdgcn_mfma_f32_16x16x32_bf16(
      __builtin_bit_cast(bf16x8, a), __builtin_bit_cast(bf16x8, b), c, 0, 0, 0);
}
DEV void wait_lds() {
  asm volatile("s_waitcnt lgkmcnt(0)" ::: "memory");
  __builtin_amdgcn_sched_barrier(0);
}

// A-fragment of W^T for dout-column `col`, k-rows k0..k0+7.  W row-major [K][N], f32.
DEV u16x8 build_frag(const float* W, int N, int k0, int col, float scale) {
  u16x8 f;
#pragma unroll
  for (int e = 0; e < 8; ++e)
    f[e] = f2bf(W[(k0 + e) * N + col] * scale);
  return f;
}
// multiply fragment rows k by gv[e] (LN gamma fold)
DEV u16x8 fold_frag(u16x8 f, const float* gv) {
  u16x8 o;
#pragma unroll
  for (int e = 0; e < 8; ++e) {
    union { u32 i; float v; } u; u.i = ((u32)f[e]) << 16;
    o[e] = f2bf(u.v * gv[e]);
  }
  return o;
}

// D-layout (lane: row=l&15, d=16H+4g+i in regs) -> B-fragment (lane: row=l&15, d=8g+j in elems)
// via per-wave LDS repack.  Row stride 20 dwords keeps 16B alignment.
DEV u16x8 conv_std(u32* buf, int r15, int lg, f32x4 a0, f32x4 a1) {
  const int wb = r15 * 20 + 2 * lg;
  buf[wb + 0] = pk2(a0[0], a0[1]);
  buf[wb + 1] = pk2(a0[2], a0[3]);
  buf[wb + 8] = pk2(a1[0], a1[1]);
  buf[wb + 9] = pk2(a1[2], a1[3]);
  wait_lds();
  uint4 rd = *(const uint4*)(buf + r15 * 20 + 4 * lg);
  return __builtin_bit_cast(u16x8, rd);
}

// q and k repacked with a single LDS wait
DEV void conv_qk(u32* bq_, u32* bk_, int r15, int lg,
                 f32x4 q0, f32x4 q1, f32x4 k0, f32x4 k1,
                 u16x8& qf, u16x8& kf) {
  const int wb = r15 * 20 + 2 * lg;
  bq_[wb + 0] = pk2(q0[0], q0[1]);
  bq_[wb + 1] = pk2(q0[2], q0[3]);
  bq_[wb + 8] = pk2(q1[0], q1[1]);
  bq_[wb + 9] = pk2(q1[2], q1[3]);
  bk_[wb + 0] = pk2(k0[0], k0[1]);
  bk_[wb + 1] = pk2(k0[2], k0[3]);
  bk_[wb + 8] = pk2(k1[0], k1[1]);
  bk_[wb + 9] = pk2(k1[2], k1[3]);
  wait_lds();
  qf = __builtin_bit_cast(u16x8, *(const uint4*)(bq_ + r15 * 20 + 4 * lg));
  kf = __builtin_bit_cast(u16x8, *(const uint4*)(bk_ + r15 * 20 + 4 * lg));
}

DEV void ln_stats(f32x4 a, f32x4 b, float& rs, float& nm) {
  float s1 = 0.f, s2 = 0.f;
#pragma unroll
  for (int i = 0; i < 4; ++i) { s1 += a[i]; s2 = fmaf(a[i], a[i], s2); }
#pragma unroll
  for (int i = 0; i < 4; ++i) { s1 += b[i]; s2 = fmaf(b[i], b[i], s2); }
  s1 += __shfl_xor(s1, 16); s2 += __shfl_xor(s2, 16);
  s1 += __shfl_xor(s1, 32); s2 += __shfl_xor(s2, 32);
  const float m   = s1 * 0.03125f;
  const float var = fmaf(s2, 0.03125f, -m * m);
  rs = __builtin_amdgcn_rsqf(var + 1e-5f);
  nm = -m * rs;
}

// gelu(u) = u * e / (e+1),  e = exp(1.5957691216*(u + 0.044715 u^3))
DEV float gelu_t(float u) {
  const float u2 = u * u;
  float z2 = u * fmaf(u2, 0.07135481f, 1.59576912f);
  z2 = fminf(z2, 80.f);
  const float e = __builtin_amdgcn_exp2f(z2 * LOG2E);
  return u * e * __builtin_amdgcn_rcpf(e + 1.0f);
}

__global__ __launch_bounds__(256) void vit_fused(
    const float* __restrict__ x,
    const float* __restrict__ wpe, const float* __restrict__ bpe,
    const float* __restrict__ pos,
    const float* __restrict__ ln1g, const float* __restrict__ ln1b,
    const float* __restrict__ wq, const float* __restrict__ bq,
    const float* __restrict__ wk, const float* __restrict__ bk,
    const float* __restrict__ wv, const float* __restrict__ bv,
    const float* __restrict__ wo, const float* __restrict__ bo,
    const float* __restrict__ ln2g, const float* __restrict__ ln2b,
    const float* __restrict__ w1, const float* __restrict__ bf1,
    const float* __restrict__ w2, const float* __restrict__ bf2,
    float* __restrict__ out) {
  const int tid = (int)threadIdx.x;
  const int wid = tid >> 6;
  const int l   = tid & 63;
  const int r15 = l & 15;        // row within 16-row tile (= 4 batches x 4 tokens)
  const int lg  = l >> 4;        // lane group 0..3
  const int tk  = l & 3;         // token index of this row

  __shared__ alignas(16) u32   s_conv[4][2][320];  // 10.0 KB
  __shared__ alignas(16) float s_vh[4][576];       //  9.0 KB  v-tile [16][36] f32, unioned with MLP h-buffer
  __shared__ alignas(16) float s_at[4][64];        //  1.0 KB  attn weights
  u32*   bufA = s_conv[wid][0];
  u32*   bufB = s_conv[wid][1];
  float* vS   = s_vh[wid];
  u32*   hB   = (u32*)s_vh[wid];
  float* aT   = s_at[wid];

  // ---------------- init: persistent weight fragments + folded biases ----------------
  float g1v[8], g2v[8];
#pragma unroll
  for (int e = 0; e < 8; ++e) { g1v[e] = ln1g[8 * lg + e]; g2v[e] = ln2g[8 * lg + e]; }
  const u16x8 b1f = pack8(*(const f32x4*)(ln1b + 8 * lg), *(const f32x4*)(ln1b + 8 * lg + 4));
  const u16x8 b2f = pack8(*(const f32x4*)(ln2b + 8 * lg), *(const f32x4*)(ln2b + 8 * lg + 4));

  u16x8 wpeF[2], wqF[2], wkF[2], wvF[2], woF[2], w1F[4], w2F[2][2];
  f32x4 comboC[2], bqC[2], bkC[2], bvC[2], boC[2], bf2C[2], bf1C[4];

#pragma unroll
  for (int H = 0; H < 2; ++H) {
    const int dc  = 16 * H + 4 * lg;
    const int col = 16 * H + r15;
    wpeF[H]   = build_frag(wpe, 32, 8 * lg, col, 1.f);
    woF[H]    = build_frag(wo,  32, 8 * lg, col, 1.f);
    w2F[0][H] = build_frag(w2,  32, 8 * lg,      col, 1.f);
    w2F[1][H] = build_frag(w2,  32, 32 + 8 * lg, col, 1.f);
    f32x4 cq, ck, cv, cmb, cbo, cb2;
#pragma unroll
    for (int i = 0; i < 4; ++i) {
      const int d = dc + i;
      cmb[i] = bpe[d] + pos[tk * 32 + d];
      cq[i]  = SCALE_Q * bq[d];
      ck[i]  = bk[d];
      cv[i]  = bv[d];
      cbo[i] = bo[d];
      cb2[i] = bf2[d];
    }
    comboC[H] = cmb; boC[H] = cbo; bf2C[H] = cb2;
    const u16x8 rq = build_frag(wq, 32, 8 * lg, col, SCALE_Q);
    const u16x8 rk = build_frag(wk, 32, 8 * lg, col, 1.f);
    const u16x8 rv = build_frag(wv, 32, 8 * lg, col, 1.f);
    bqC[H] = mfma(rq, b1f, cq);        // SCALE*(bq + ln1_b @ wq)
    bkC[H] = mfma(rk, b1f, ck);
    bvC[H] = mfma(rv, b1f, cv);
    wqF[H] = fold_frag(rq, g1v);       // gamma fold
    wkF[H] = fold_frag(rk, g1v);
    wvF[H] = fold_frag(rv, g1v);
  }
#pragma unroll
  for (int Hp = 0; Hp < 4; ++Hp) {
    const int col = 16 * Hp + r15;
    const u16x8 r1 = build_frag(w1, 64, 8 * lg, col, 1.f);
    f32x4 c1;
#pragma unroll
    for (int i = 0; i < 4; ++i) c1[i] = bf1[16 * Hp + 4 * lg + i];
    bf1C[Hp] = mfma(r1, b2f, c1);      // bf1 + ln2_b @ w1
    w1F[Hp]  = fold_frag(r1, g2v);
  }

  // ---------------- main loop ----------------
  const f32x4 zero4 = {0.f, 0.f, 0.f, 0.f};
  const int stride = (int)(gridDim.x << 2);
  int tile = (int)(blockIdx.x << 2) | wid;

  const float* xp = x + (size_t)(tile * 16 + r15) * 32 + 8 * lg;
  f32x4 xv0 = *(const f32x4*)(xp);
  f32x4 xv1 = *(const f32x4*)(xp + 4);
  for (; tile < NT; tile += stride) {
    const int nxt = tile + stride;
    f32x4 nx0 = xv0, nx1 = xv1;
    if (nxt < NT) {
      const float* np_ = x + (size_t)(nxt * 16 + r15) * 32 + 8 * lg;
      nx0 = *(const f32x4*)(np_);
      nx1 = *(const f32x4*)(np_ + 4);
    }
    const u16x8 xf = pack8(xv0, xv1);

    // patch-embed + pos (+b_pe) : residual base x1
    f32x4 x1a = mfma(wpeF[0], xf, comboC[0]);
    f32x4 x1b = mfma(wpeF[1], xf, comboC[1]);

    // LN1 (gamma/beta folded into wq/wk/wv + C)
    float rs, nm;
    ln_stats(x1a, x1b, rs, nm);
    f32x4 ya, yb;
#pragma unroll
    for (int i = 0; i < 4; ++i) { ya[i] = fmaf(x1a[i], rs, nm); yb[i] = fmaf(x1b[i], rs, nm); }
    const u16x8 xaf = conv_std(bufA, r15, lg, ya, yb);

    const f32x4 qa0 = mfma(wqF[0], xaf, bqC[0]);
    const f32x4 qa1 = mfma(wqF[1], xaf, bqC[1]);
    const f32x4 ka0 = mfma(wkF[0], xaf, bkC[0]);
    const f32x4 ka1 = mfma(wkF[1], xaf, bkC[1]);
    const f32x4 va0 = mfma(wvF[0], xaf, bvC[0]);
    const f32x4 va1 = mfma(wvF[1], xaf, bvC[1]);

    // stage v (f32, D-layout) into the unioned v/h buffer; covered by the qk wait
    *(f32x4*)(vS + r15 * 36 + 4 * lg)      = va0;
    *(f32x4*)(vS + r15 * 36 + 16 + 4 * lg) = va1;

    // q,k -> std B-fragments (single LDS wait)
    u16x8 qf, kf;
    conv_qk(bufB, bufA, r15, lg, qa0, qa1, ka0, ka1, qf, kf);

    // scores: D[col=q-row r15][m=k-row 4lg+i]; owner lanes lg==r15>>2 hold the in-batch 4
    const f32x4 sc = mfma(kf, qf, zero4);
    {
      const float mx = fmaxf(fmaxf(sc[0], sc[1]), fmaxf(sc[2], sc[3]));
      const float e0 = __builtin_amdgcn_exp2f((sc[0] - mx) * LOG2E);
      const float e1 = __builtin_amdgcn_exp2f((sc[1] - mx) * LOG2E);
      const float e2 = __builtin_amdgcn_exp2f((sc[2] - mx) * LOG2E);
      const float e3 = __builtin_amdgcn_exp2f((sc[3] - mx) * LOG2E);
      const float rc = __builtin_amdgcn_rcpf((e0 + e1) + (e2 + e3));
      f32x4 p; p[0] = e0 * rc; p[1] = e1 * rc; p[2] = e2 * rc; p[3] = e3 * rc;
      if (lg == (r15 >> 2)) *(f32x4*)(aT + 4 * r15) = p;   // attn[q-row][j=0..3]
    }
    wait_lds();

    // mixed[r15][d] = sum_j attn[r15][j] * v[(r15&12)+j][d]
    const f32x4 atv = *(const f32x4*)(aT + 4 * r15);
    f32x4 m0 = zero4, m1 = zero4;
#pragma unroll
    for (int j = 0; j < 4; ++j) {
      const f32x4 v0 = *(const f32x4*)(vS + ((r15 & 12) + j) * 36 + 4 * lg);
      const f32x4 v1 = *(const f32x4*)(vS + ((r15 & 12) + j) * 36 + 16 + 4 * lg);
      m0 += atv[j] * v0;
      m1 += atv[j] * v1;
    }
    const u16x8 mf = conv_std(bufB, r15, lg, m0, m1);

    // x2 = x1 + mixed @ wo + bo   (residual via C-operand)
    const f32x4 x2a = mfma(woF[0], mf, x1a) + boC[0];
    const f32x4 x2b = mfma(woF[1], mf, x1b) + boC[1];

    // LN2 (folded) -> MLP
    ln_stats(x2a, x2b, rs, nm);
#pragma unroll
    for (int i = 0; i < 4; ++i) { ya[i] = fmaf(x2a[i], rs, nm); yb[i] = fmaf(x2b[i], rs, nm); }
    const u16x8 xbf = conv_std(bufA, r15, lg, ya, yb);

#pragma unroll
    for (int Hp = 0; Hp < 4; ++Hp) {
      const f32x4 h = mfma(w1F[Hp], xbf, bf1C[Hp]);
      const int hb = r15 * 36 + 8 * Hp + 2 * lg;
      hB[hb]     = pk2(gelu_t(h[0]), gelu_t(h[1]));
      hB[hb + 1] = pk2(gelu_t(h[2]), gelu_t(h[3]));
    }
    wait_lds();
    const uint4 h0r = *(const uint4*)(hB + r15 * 36 + 4 * lg);
    const uint4 h1r = *(const uint4*)(hB + r15 * 36 + 16 + 4 * lg);
    const u16x8 hf0 = __builtin_bit_cast(u16x8, h0r);
    const u16x8 hf1 = __builtin_bit_cast(u16x8, h1r);

    // out = x2 + h @ w2 + bf2
    f32x4 o0 = x2a + bf2C[0];
    f32x4 o1 = x2b + bf2C[1];
    o0 = mfma(w2F[0][0], hf0, o0);
    o0 = mfma(w2F[1][0], hf1, o0);
    o1 = mfma(w2F[0][1], hf0, o1);
    o1 = mfma(w2F[1][1], hf1, o1);

    // f32 output store: row stride 32 floats; lane covers features 4lg..+3 / 16+4lg..+3
    float* op = out + (size_t)(tile * 16 + r15) * 32;
    *(f32x4*)(op + 4 * lg)      = o0;
    *(f32x4*)(op + 16 + 4 * lg) = o1;

    xv0 = nx0; xv1 = nx1;
  }
}

extern "C" void kernel_launch(void* const* d_in, const int* in_sizes, int n_in,
                              void* d_out, int out_size, void* d_ws, size_t ws_size,
                              hipStream_t stream) {
  (void)in_sizes; (void)n_in; (void)d_ws; (void)ws_size; (void)out_size;
  const float* x    = (const float*)d_in[0];
  const float* wpe  = (const float*)d_in[1];
  const float* bpe  = (const float*)d_in[2];
  const float* pos  = (const float*)d_in[3];
  const float* ln1g = (const float*)d_in[4];
  const float* ln1b = (const float*)d_in[5];
  const float* wq   = (const float*)d_in[6];
  const float* bq   = (const float*)d_in[7];
  const float* wk   = (const float*)d_in[8];
  const float* bk   = (const float*)d_in[9];
  const float* wv   = (const float*)d_in[10];
  const float* bv   = (const float*)d_in[11];
  const float* wo   = (const float*)d_in[12];
  const float* bo   = (const float*)d_in[13];
  const float* ln2g = (const float*)d_in[14];
  const float* ln2b = (const float*)d_in[15];
  const float* w1   = (const float*)d_in[16];
  const float* bf1  = (const float*)d_in[17];
  const float* w2   = (const float*)d_in[18];
  const float* bf2  = (const float*)d_in[19];

  vit_fused<<<2048, 256, 0, stream>>>(x, wpe, bpe, pos, ln1g, ln1b, wq, bq, wk, bk,
                                      wv, bv, wo, bo, ln2g, ln2b, w1, bf1, w2, bf2,
                                      (float*)d_out);
}

// Round 8
// 78.387 us; speedup vs baseline: 1.1693x; 1.1693x over previous
//
#include <hip/hip_runtime.h>
#include <hip/hip_bf16.h>

typedef float          f32x4  __attribute__((ext_vector_type(4)));
typedef __bf16         bf16x8 __attribute__((ext_vector_type(8)));
typedef unsigned short u16x8  __attribute__((ext_vector_type(8)));
typedef unsigned int   u32;

#define DEV static __device__ __forceinline__

static constexpr int   NT       = 65536;            // (262144*4)/16 16-row tiles
static constexpr float SCALE_Q2 = 0.2550349f;       // (1/sqrt(32)) * log2(e)  -> scores in log2 units

DEV unsigned short f2bf(float f) {
  return __builtin_bit_cast(unsigned short, __float2bfloat16(f));
}
// single-instruction RNE pair convert (gfx950); pure VALU, register dataflow only
DEV u32 pk2(float lo, float hi) {
  u32 r;
  asm("v_cvt_pk_bf16_f32 %0, %1, %2" : "=v"(r) : "v"(lo), "v"(hi));
  return r;
}

DEV u16x8 pack8(f32x4 a, f32x4 b) {
  uint4 q;
  q.x = pk2(a[0], a[1]); q.y = pk2(a[2], a[3]);
  q.z = pk2(b[0], b[1]); q.w = pk2(b[2], b[3]);
  return __builtin_bit_cast(u16x8, q);
}

DEV f32x4 mfma(u16x8 a, u16x8 b, f32x4 c) {
  return __builtin_amdgcn_mfma_f32_16x16x32_bf16(
      __builtin_bit_cast(bf16x8, a), __builtin_bit_cast(bf16x8, b), c, 0, 0, 0);
}
DEV void wait_lds() {
  asm volatile("s_waitcnt lgkmcnt(0)" ::: "memory");
  __builtin_amdgcn_sched_barrier(0);
}

// A-fragment of W^T for dout-column `col`, k-rows k0..k0+7.  W row-major [K][N], f32.
DEV u16x8 build_frag(const float* W, int N, int k0, int col, float scale) {
  u16x8 f;
#pragma unroll
  for (int e = 0; e < 8; ++e)
    f[e] = f2bf(W[(k0 + e) * N + col] * scale);
  return f;
}
// multiply fragment rows k by gv[e] (LN gamma fold)
DEV u16x8 fold_frag(u16x8 f, const float* gv) {
  u16x8 o;
#pragma unroll
  for (int e = 0; e < 8; ++e) {
    union { u32 i; float v; } u; u.i = ((u32)f[e]) << 16;
    o[e] = f2bf(u.v * gv[e]);
  }
  return o;
}

// D-layout (lane: row=l&15, d=16H+4g+i in regs) -> B-fragment (lane: row=l&15, d=8g+j in elems)
// via per-wave LDS repack.  Row stride 20 dwords keeps 16B alignment.
DEV u16x8 conv_std(u32* buf, int r15, int lg, f32x4 a0, f32x4 a1) {
  const int wb = r15 * 20 + 2 * lg;
  buf[wb + 0] = pk2(a0[0], a0[1]);
  buf[wb + 1] = pk2(a0[2], a0[3]);
  buf[wb + 8] = pk2(a1[0], a1[1]);
  buf[wb + 9] = pk2(a1[2], a1[3]);
  wait_lds();
  uint4 rd = *(const uint4*)(buf + r15 * 20 + 4 * lg);
  return __builtin_bit_cast(u16x8, rd);
}

// q and k repacked with a single LDS wait
DEV void conv_qk(u32* bq_, u32* bk_, int r15, int lg,
                 f32x4 q0, f32x4 q1, f32x4 k0, f32x4 k1,
                 u16x8& qf, u16x8& kf) {
  const int wb = r15 * 20 + 2 * lg;
  bq_[wb + 0] = pk2(q0[0], q0[1]);
  bq_[wb + 1] = pk2(q0[2], q0[3]);
  bq_[wb + 8] = pk2(q1[0], q1[1]);
  bq_[wb + 9] = pk2(q1[2], q1[3]);
  bk_[wb + 0] = pk2(k0[0], k0[1]);
  bk_[wb + 1] = pk2(k0[2], k0[3]);
  bk_[wb + 8] = pk2(k1[0], k1[1]);
  bk_[wb + 9] = pk2(k1[2], k1[3]);
  wait_lds();
  qf = __builtin_bit_cast(u16x8, *(const uint4*)(bq_ + r15 * 20 + 4 * lg));
  kf = __builtin_bit_cast(u16x8, *(const uint4*)(bk_ + r15 * 20 + 4 * lg));
}

DEV void ln_stats(f32x4 a, f32x4 b, float& rs, float& nm) {
  float s1 = 0.f, s2 = 0.f;
#pragma unroll
  for (int i = 0; i < 4; ++i) { s1 += a[i]; s2 = fmaf(a[i], a[i], s2); }
#pragma unroll
  for (int i = 0; i < 4; ++i) { s1 += b[i]; s2 = fmaf(b[i], b[i], s2); }
  s1 += __shfl_xor(s1, 16); s2 += __shfl_xor(s2, 16);
  s1 += __shfl_xor(s1, 32); s2 += __shfl_xor(s2, 32);
  const float m   = s1 * 0.03125f;
  const float var = fmaf(s2, 0.03125f, -m * m);
  rs = __builtin_amdgcn_rsqf(var + 1e-5f);
  nm = -m * rs;
}

// gelu(u) = u - u/(e+1),  e = exp2(u*(2.3022083 + 0.1029428 u^2))   (LOG2E pre-folded)
// inf-safe: e=inf -> rcp=0 -> u;  e->0 -> u-u=0.
DEV float gelu_t(float u) {
  const float z = u * fmaf(u * u, 0.1029428f, 2.3022083f);
  const float e = __builtin_amdgcn_exp2f(z);
  return fmaf(-u, __builtin_amdgcn_rcpf(e + 1.0f), u);
}

__global__ __launch_bounds__(256) void vit_fused(
    const float* __restrict__ x,
    const float* __restrict__ wpe, const float* __restrict__ bpe,
    const float* __restrict__ pos,
    const float* __restrict__ ln1g, const float* __restrict__ ln1b,
    const float* __restrict__ wq, const float* __restrict__ bq,
    const float* __restrict__ wk, const float* __restrict__ bk,
    const float* __restrict__ wv, const float* __restrict__ bv,
    const float* __restrict__ wo, const float* __restrict__ bo,
    const float* __restrict__ ln2g, const float* __restrict__ ln2b,
    const float* __restrict__ w1, const float* __restrict__ bf1,
    const float* __restrict__ w2, const float* __restrict__ bf2,
    float* __restrict__ out) {
  const int tid = (int)threadIdx.x;
  const int wid = tid >> 6;
  const int l   = tid & 63;
  const int r15 = l & 15;        // row within 16-row tile (= 4 batches x 4 tokens)
  const int lg  = l >> 4;        // lane group 0..3
  const int tk  = l & 3;         // token index of this row

  __shared__ alignas(16) u32   s_conv[4][2][320];  // 10.0 KB
  __shared__ alignas(16) float s_vh[4][576];       //  9.0 KB  v-tile [16][36] f32, unioned with MLP h-buffer
  __shared__ alignas(16) float s_at[4][64];        //  1.0 KB  attn weights
  u32*   bufA = s_conv[wid][0];
  u32*   bufB = s_conv[wid][1];
  float* vS   = s_vh[wid];
  u32*   hB   = (u32*)s_vh[wid];
  float* aT   = s_at[wid];

  // ---------------- init: persistent weight fragments + folded biases ----------------
  float g1v[8], g2v[8];
#pragma unroll
  for (int e = 0; e < 8; ++e) { g1v[e] = ln1g[8 * lg + e]; g2v[e] = ln2g[8 * lg + e]; }
  const u16x8 b1f = pack8(*(const f32x4*)(ln1b + 8 * lg), *(const f32x4*)(ln1b + 8 * lg + 4));
  const u16x8 b2f = pack8(*(const f32x4*)(ln2b + 8 * lg), *(const f32x4*)(ln2b + 8 * lg + 4));

  u16x8 wpeF[2], wqF[2], wkF[2], wvF[2], woF[2], w1F[4], w2F[2][2];
  f32x4 comboC[2], bqC[2], bkC[2], bvC[2], boC[2], bf2C[2], bf1C[4];

#pragma unroll
  for (int H = 0; H < 2; ++H) {
    const int dc  = 16 * H + 4 * lg;
    const int col = 16 * H + r15;
    wpeF[H]   = build_frag(wpe, 32, 8 * lg, col, 1.f);
    woF[H]    = build_frag(wo,  32, 8 * lg, col, 1.f);
    w2F[0][H] = build_frag(w2,  32, 8 * lg,      col, 1.f);
    w2F[1][H] = build_frag(w2,  32, 32 + 8 * lg, col, 1.f);
    f32x4 cq, ck, cv, cmb, cbo, cb2;
#pragma unroll
    for (int i = 0; i < 4; ++i) {
      const int d = dc + i;
      cmb[i] = bpe[d] + pos[tk * 32 + d];
      cq[i]  = SCALE_Q2 * bq[d];
      ck[i]  = bk[d];
      cv[i]  = bv[d];
      cbo[i] = bo[d];
      cb2[i] = bf2[d];
    }
    comboC[H] = cmb; boC[H] = cbo; bf2C[H] = cb2;
    const u16x8 rq = build_frag(wq, 32, 8 * lg, col, SCALE_Q2);
    const u16x8 rk = build_frag(wk, 32, 8 * lg, col, 1.f);
    const u16x8 rv = build_frag(wv, 32, 8 * lg, col, 1.f);
    bqC[H] = mfma(rq, b1f, cq);        // SCALE'*(bq + ln1_b @ wq)
    bkC[H] = mfma(rk, b1f, ck);
    bvC[H] = mfma(rv, b1f, cv);
    wqF[H] = fold_frag(rq, g1v);       // gamma fold
    wkF[H] = fold_frag(rk, g1v);
    wvF[H] = fold_frag(rv, g1v);
  }
#pragma unroll
  for (int Hp = 0; Hp < 4; ++Hp) {
    const int col = 16 * Hp + r15;
    const u16x8 r1 = build_frag(w1, 64, 8 * lg, col, 1.f);
    f32x4 c1;
#pragma unroll
    for (int i = 0; i < 4; ++i) c1[i] = bf1[16 * Hp + 4 * lg + i];
    bf1C[Hp] = mfma(r1, b2f, c1);      // bf1 + ln2_b @ w1
    w1F[Hp]  = fold_frag(r1, g2v);
  }

  // ---------------- main loop ----------------
  const f32x4 zero4 = {0.f, 0.f, 0.f, 0.f};
  const int stride = (int)(gridDim.x << 2);
  int tile = (int)(blockIdx.x << 2) | wid;

  const float* xp = x + (size_t)(tile * 16 + r15) * 32 + 8 * lg;
  f32x4 xv0 = *(const f32x4*)(xp);
  f32x4 xv1 = *(const f32x4*)(xp + 4);
  for (; tile < NT; tile += stride) {
    const int nxt = tile + stride;
    f32x4 nx0 = xv0, nx1 = xv1;
    if (nxt < NT) {
      const float* np_ = x + (size_t)(nxt * 16 + r15) * 32 + 8 * lg;
      nx0 = *(const f32x4*)(np_);
      nx1 = *(const f32x4*)(np_ + 4);
    }
    const u16x8 xf = pack8(xv0, xv1);

    // patch-embed + pos (+b_pe) : residual base x1
    f32x4 x1a = mfma(wpeF[0], xf, comboC[0]);
    f32x4 x1b = mfma(wpeF[1], xf, comboC[1]);

    // LN1 (gamma/beta folded into wq/wk/wv + C)
    float rs, nm;
    ln_stats(x1a, x1b, rs, nm);
    f32x4 ya, yb;
#pragma unroll
    for (int i = 0; i < 4; ++i) { ya[i] = fmaf(x1a[i], rs, nm); yb[i] = fmaf(x1b[i], rs, nm); }
    const u16x8 xaf = conv_std(bufA, r15, lg, ya, yb);

    const f32x4 qa0 = mfma(wqF[0], xaf, bqC[0]);
    const f32x4 qa1 = mfma(wqF[1], xaf, bqC[1]);
    const f32x4 ka0 = mfma(wkF[0], xaf, bkC[0]);
    const f32x4 ka1 = mfma(wkF[1], xaf, bkC[1]);
    const f32x4 va0 = mfma(wvF[0], xaf, bvC[0]);
    const f32x4 va1 = mfma(wvF[1], xaf, bvC[1]);

    // stage v (f32, D-layout) into the unioned v/h buffer; covered by the qk wait
    *(f32x4*)(vS + r15 * 36 + 4 * lg)      = va0;
    *(f32x4*)(vS + r15 * 36 + 16 + 4 * lg) = va1;

    // q,k -> std B-fragments (single LDS wait)
    u16x8 qf, kf;
    conv_qk(bufB, bufA, r15, lg, qa0, qa1, ka0, ka1, qf, kf);

    // scores (log2 units): D[col=q-row r15][m=k-row 4lg+i]; owner lanes lg==r15>>2
    const f32x4 sc = mfma(kf, qf, zero4);
    {
      const float mx = fmaxf(fmaxf(sc[0], sc[1]), fmaxf(sc[2], sc[3]));
      const float e0 = __builtin_amdgcn_exp2f(sc[0] - mx);
      const float e1 = __builtin_amdgcn_exp2f(sc[1] - mx);
      const float e2 = __builtin_amdgcn_exp2f(sc[2] - mx);
      const float e3 = __builtin_amdgcn_exp2f(sc[3] - mx);
      const float rc = __builtin_amdgcn_rcpf((e0 + e1) + (e2 + e3));
      f32x4 p; p[0] = e0 * rc; p[1] = e1 * rc; p[2] = e2 * rc; p[3] = e3 * rc;
      if (lg == (r15 >> 2)) *(f32x4*)(aT + 4 * r15) = p;   // attn[q-row][j=0..3]
    }
    wait_lds();

    // mixed[r15][d] = sum_j attn[r15][j] * v[(r15&12)+j][d]
    const f32x4 atv = *(const f32x4*)(aT + 4 * r15);
    f32x4 m0 = zero4, m1 = zero4;
#pragma unroll
    for (int j = 0; j < 4; ++j) {
      const f32x4 v0 = *(const f32x4*)(vS + ((r15 & 12) + j) * 36 + 4 * lg);
      const f32x4 v1 = *(const f32x4*)(vS + ((r15 & 12) + j) * 36 + 16 + 4 * lg);
      m0 += atv[j] * v0;
      m1 += atv[j] * v1;
    }
    const u16x8 mf = conv_std(bufB, r15, lg, m0, m1);

    // x2 = x1 + mixed @ wo + bo   (residual via C-operand)
    const f32x4 x2a = mfma(woF[0], mf, x1a) + boC[0];
    const f32x4 x2b = mfma(woF[1], mf, x1b) + boC[1];

    // LN2 (folded) -> MLP
    ln_stats(x2a, x2b, rs, nm);
#pragma unroll
    for (int i = 0; i < 4; ++i) { ya[i] = fmaf(x2a[i], rs, nm); yb[i] = fmaf(x2b[i], rs, nm); }
    const u16x8 xbf = conv_std(bufA, r15, lg, ya, yb);

#pragma unroll
    for (int Hp = 0; Hp < 4; ++Hp) {
      const f32x4 h = mfma(w1F[Hp], xbf, bf1C[Hp]);
      const int hb = r15 * 36 + 8 * Hp + 2 * lg;
      hB[hb]     = pk2(gelu_t(h[0]), gelu_t(h[1]));
      hB[hb + 1] = pk2(gelu_t(h[2]), gelu_t(h[3]));
    }
    wait_lds();
    const uint4 h0r = *(const uint4*)(hB + r15 * 36 + 4 * lg);
    const uint4 h1r = *(const uint4*)(hB + r15 * 36 + 16 + 4 * lg);
    const u16x8 hf0 = __builtin_bit_cast(u16x8, h0r);
    const u16x8 hf1 = __builtin_bit_cast(u16x8, h1r);

    // out = x2 + h @ w2 + bf2
    f32x4 o0 = x2a + bf2C[0];
    f32x4 o1 = x2b + bf2C[1];
    o0 = mfma(w2F[0][0], hf0, o0);
    o0 = mfma(w2F[1][0], hf1, o0);
    o1 = mfma(w2F[0][1], hf0, o1);
    o1 = mfma(w2F[1][1], hf1, o1);

    // f32 output store: row stride 32 floats; lane covers features 4lg..+3 / 16+4lg..+3
    float* op = out + (size_t)(tile * 16 + r15) * 32;
    *(f32x4*)(op + 4 * lg)      = o0;
    *(f32x4*)(op + 16 + 4 * lg) = o1;

    xv0 = nx0; xv1 = nx1;
  }
}

extern "C" void kernel_launch(void* const* d_in, const int* in_sizes, int n_in,
                              void* d_out, int out_size, void* d_ws, size_t ws_size,
                              hipStream_t stream) {
  (void)in_sizes; (void)n_in; (void)d_ws; (void)ws_size; (void)out_size;
  const float* x    = (const float*)d_in[0];
  const float* wpe  = (const float*)d_in[1];
  const float* bpe  = (const float*)d_in[2];
  const float* pos  = (const float*)d_in[3];
  const float* ln1g = (const float*)d_in[4];
  const float* ln1b = (const float*)d_in[5];
  const float* wq   = (const float*)d_in[6];
  const float* bq   = (const float*)d_in[7];
  const float* wk   = (const float*)d_in[8];
  const float* bk   = (const float*)d_in[9];
  const float* wv   = (const float*)d_in[10];
  const float* bv   = (const float*)d_in[11];
  const float* wo   = (const float*)d_in[12];
  const float* bo   = (const float*)d_in[13];
  const float* ln2g = (const float*)d_in[14];
  const float* ln2b = (const float*)d_in[15];
  const float* w1   = (const float*)d_in[16];
  const float* bf1  = (const float*)d_in[17];
  const float* w2   = (const float*)d_in[18];
  const float* bf2  = (const float*)d_in[19];

  vit_fused<<<1024, 256, 0, stream>>>(x, wpe, bpe, pos, ln1g, ln1b, wq, bq, wk, bk,
                                      wv, bv, wo, bo, ln2g, ln2b, w1, bf1, w2, bf2,
                                      (float*)d_out);
}